// Round 1
// baseline (19808.252 us; speedup 1.0000x reference)
//
#include <hip/hip_runtime.h>

// ---------------------------------------------------------------------------
// 2-layer LSTM generator, persistent kernel.
// Parallel layout:
//   grid 256 blocks x 512 threads (8 waves). 1 block/CU (LDS-limited).
//   Each wave handles R=8 batch elements; lane k (<50) owns hidden unit k
//   for both layers; lanes 50..63 shadow lane 49 (results discarded).
//   Weights live in LDS transposed so the unit dim is lane-contiguous
//   (conflict-free ds_read_b128); shared activations are broadcast reads.
// ---------------------------------------------------------------------------

#define H      50
#define F      3
#define T_TF   512
#define T_ALL  1024
#define BATCH  16384
#define WAVES  8
#define R      8                       // batch elements per lane
#define BLK    (WAVES * 64)            // 512 threads
#define BPB    (WAVES * R)             // 64 batch / block
#define GRID   (BATCH / BPB)           // 256 blocks

// LDS layout (float offsets)
#define W1_SZ   (53 * H * 4)           // [53 rows][50 units][4 gates] = 10600
#define W2_SZ   (100 * H * 4)          // [100 rows][50][4]            = 20000
#define WLIN_OFF (W1_SZ + W2_SZ)       // 30600
#define WLIN_SZ (H * 4)                // 200
#define EX_OFF  (WLIN_OFF + WLIN_SZ)   // 30800
#define EX_ROWS 104                    // 0..49 h1 | 50..99 h2 | 100..102 x | 103 pad
#define EX_PW   (EX_ROWS * R)          // 832 floats per wave
#define LDS_FLOATS (EX_OFF + WAVES * EX_PW)   // 37456 floats = 149824 B
#define LDS_BYTES  (LDS_FLOATS * 4)

__device__ __forceinline__ float fast_sigmoid(float x) {
    float e = __builtin_amdgcn_exp2f(-1.44269504089f * x);   // e^-x
    return __builtin_amdgcn_rcpf(1.0f + e);
}
__device__ __forceinline__ float fast_tanh(float x) {
    float e = __builtin_amdgcn_exp2f(2.88539008178f * x);    // e^{2x}
    return 1.0f - 2.0f * __builtin_amdgcn_rcpf(1.0f + e);
}

// 4 gates x 8 batch FMAs for one input element
#define FMA8(W, U0, U1)                                                         \
  {                                                                             \
    aI[0] += W.x*U0.x; aF[0] += W.y*U0.x; aG[0] += W.z*U0.x; aO[0] += W.w*U0.x; \
    aI[1] += W.x*U0.y; aF[1] += W.y*U0.y; aG[1] += W.z*U0.y; aO[1] += W.w*U0.y; \
    aI[2] += W.x*U0.z; aF[2] += W.y*U0.z; aG[2] += W.z*U0.z; aO[2] += W.w*U0.z; \
    aI[3] += W.x*U0.w; aF[3] += W.y*U0.w; aG[3] += W.z*U0.w; aO[3] += W.w*U0.w; \
    aI[4] += W.x*U1.x; aF[4] += W.y*U1.x; aG[4] += W.z*U1.x; aO[4] += W.w*U1.x; \
    aI[5] += W.x*U1.y; aF[5] += W.y*U1.y; aG[5] += W.z*U1.y; aO[5] += W.w*U1.y; \
    aI[6] += W.x*U1.z; aF[6] += W.y*U1.z; aG[6] += W.z*U1.z; aO[6] += W.w*U1.z; \
    aI[7] += W.x*U1.w; aF[7] += W.y*U1.w; aG[7] += W.z*U1.w; aO[7] += W.w*U1.w; \
  }

extern "C" __global__ void __launch_bounds__(BLK, 2)
lstm_gen_kernel(const float* __restrict__ X,
                const float* __restrict__ Wih1, const float* __restrict__ Whh1,
                const float* __restrict__ bih1, const float* __restrict__ bhh1,
                const float* __restrict__ Wih2, const float* __restrict__ Whh2,
                const float* __restrict__ bih2, const float* __restrict__ bhh2,
                const float* __restrict__ Wlin, const float* __restrict__ blin,
                float* __restrict__ OUT)
{
    extern __shared__ __align__(16) float lds[];
    const int tid  = threadIdx.x;
    const int wave = tid >> 6;
    const int lane = tid & 63;
    const int kk   = (lane < H) ? lane : (H - 1);      // clamped unit id
    const int bb   = blockIdx.x * BPB + wave * R;      // batch base of this wave

    // ---- stage weights into LDS (transposed: [row][unit][gate]) ----
    for (int i = tid; i < EX_OFF; i += BLK) {
        float v;
        if (i < W1_SZ) {                       // layer1: rows 0..49 = Whh1 cols, 50..52 = Wih1 cols
            int j = i / (H*4), rem = i % (H*4);
            int k = rem >> 2, g = rem & 3;
            int row = g * H + k;               // torch gate order i,f,g,o
            v = (j < H) ? Whh1[row * H + j] : Wih1[row * F + (j - H)];
        } else if (i < W1_SZ + W2_SZ) {        // layer2: rows 0..49 = Wih2 (input=h1), 50..99 = Whh2
            int i2 = i - W1_SZ;
            int j = i2 / (H*4), rem = i2 % (H*4);
            int k = rem >> 2, g = rem & 3;
            int row = g * H + k;
            v = (j < H) ? Wih2[row * H + j] : Whh2[row * H + (j - H)];
        } else {                               // Wlin: [unit][3 outs + pad]
            int i3 = i - (W1_SZ + W2_SZ);
            int k = i3 >> 2, g = i3 & 3;
            v = (g < F) ? Wlin[g * H + k] : 0.0f;
        }
        lds[i] = v;
    }
    for (int i = tid; i < WAVES * EX_PW; i += BLK) lds[EX_OFF + i] = 0.0f;  // h1=h2=0
    __syncthreads();

    // per-lane gate biases
    float b1[4], b2[4];
    #pragma unroll
    for (int g = 0; g < 4; ++g) {
        b1[g] = bih1[g*H + kk] + bhh1[g*H + kk];
        b2[g] = bih2[g*H + kk] + bhh2[g*H + kk];
    }
    // output lanes: lane < 24 handles (r = lane/3, o = lane%3)
    const int  ro_r = lane / 3, ro_o = lane % 3;
    const bool out_lane = (lane < 24);
    const float bl = blin[ro_o < F ? ro_o : 0];

    float* EX = lds + EX_OFF + wave * EX_PW;           // [104][8]
    const float4* W1q = (const float4*)(lds);
    const float4* W2q = (const float4*)(lds + W1_SZ);
    const float4* EXq = (const float4*)EX;
    float4* EXw = (float4*)EX;

    float c1[R], c2[R];
    #pragma unroll
    for (int r = 0; r < R; ++r) { c1[r] = 0.0f; c2[r] = 0.0f; }

    float aI[R], aF[R], aG[R], aO[R];

    for (int t = 0; t < T_ALL; ++t) {
        // ---- fetch x (teacher phase); gen phase keeps fed-back out in EX ----
        if (t < T_TF && out_lane) {
            EX[(100 + ro_o) * R + ro_r] = X[(t * BATCH + bb + ro_r) * F + ro_o];
        }
        __syncthreads();                               // S1: x + prev h visible

        // ---- layer 1 gates: [x(3);h1(50)] dot ----
        #pragma unroll
        for (int r = 0; r < R; ++r) { aI[r] = b1[0]; aF[r] = b1[1]; aG[r] = b1[2]; aO[r] = b1[3]; }
        for (int j = 0; j < H; ++j) {                  // h1 part
            float4 w  = W1q[j * H + kk];
            float4 u0 = EXq[j * 2 + 0];
            float4 u1 = EXq[j * 2 + 1];
            FMA8(w, u0, u1);
        }
        #pragma unroll
        for (int j = 0; j < F; ++j) {                  // x part
            float4 w  = W1q[(H + j) * H + kk];
            float4 u0 = EXq[(100 + j) * 2 + 0];
            float4 u1 = EXq[(100 + j) * 2 + 1];
            FMA8(w, u0, u1);
        }
        float h1n[R];
        #pragma unroll
        for (int r = 0; r < R; ++r) {
            float iv = fast_sigmoid(aI[r]);
            float fv = fast_sigmoid(aF[r]);
            float gv = fast_tanh(aG[r]);
            float ov = fast_sigmoid(aO[r]);
            c1[r]  = fv * c1[r] + iv * gv;
            h1n[r] = ov * fast_tanh(c1[r]);
        }
        __syncthreads();                               // S2: all h1 reads done
        if (lane < H) {
            EXw[lane * 2 + 0] = make_float4(h1n[0], h1n[1], h1n[2], h1n[3]);
            EXw[lane * 2 + 1] = make_float4(h1n[4], h1n[5], h1n[6], h1n[7]);
        }
        __syncthreads();                               // S3: h1_new visible

        // ---- layer 2 gates: [h1_new(50);h2(50)] dot ----
        #pragma unroll
        for (int r = 0; r < R; ++r) { aI[r] = b2[0]; aF[r] = b2[1]; aG[r] = b2[2]; aO[r] = b2[3]; }
        for (int j = 0; j < 2 * H; ++j) {
            float4 w  = W2q[j * H + kk];
            float4 u0 = EXq[j * 2 + 0];
            float4 u1 = EXq[j * 2 + 1];
            FMA8(w, u0, u1);
        }
        float h2n[R];
        #pragma unroll
        for (int r = 0; r < R; ++r) {
            float iv = fast_sigmoid(aI[r]);
            float fv = fast_sigmoid(aF[r]);
            float gv = fast_tanh(aG[r]);
            float ov = fast_sigmoid(aO[r]);
            c2[r]  = fv * c2[r] + iv * gv;
            h2n[r] = ov * fast_tanh(c2[r]);
        }
        __syncthreads();                               // S4: all h2 reads done
        if (lane < H) {
            EXw[(H + lane) * 2 + 0] = make_float4(h2n[0], h2n[1], h2n[2], h2n[3]);
            EXw[(H + lane) * 2 + 1] = make_float4(h2n[4], h2n[5], h2n[6], h2n[7]);
        }
        __syncthreads();                               // S5: h2_new visible

        // ---- linear head: out = Wlin h2 + blin; store + feed back ----
        if (out_lane) {
            float acc = bl;
            #pragma unroll 10
            for (int k = 0; k < H; ++k)
                acc += lds[WLIN_OFF + k * 4 + ro_o] * EX[(H + k) * R + ro_r];
            OUT[(t * BATCH + bb + ro_r) * F + ro_o] = acc;
            EX[(100 + ro_o) * R + ro_r] = acc;         // next-step x (gen phase)
        }
    }
}

extern "C" void kernel_launch(void* const* d_in, const int* in_sizes, int n_in,
                              void* d_out, int out_size, void* d_ws, size_t ws_size,
                              hipStream_t stream) {
    (void)in_sizes; (void)n_in; (void)d_ws; (void)ws_size;
    const float* X    = (const float*)d_in[0];
    const float* Wih1 = (const float*)d_in[1];
    const float* Whh1 = (const float*)d_in[2];
    const float* bih1 = (const float*)d_in[3];
    const float* bhh1 = (const float*)d_in[4];
    const float* Wih2 = (const float*)d_in[5];
    const float* Whh2 = (const float*)d_in[6];
    const float* bih2 = (const float*)d_in[7];
    const float* bhh2 = (const float*)d_in[8];
    const float* Wlin = (const float*)d_in[9];
    const float* blin = (const float*)d_in[10];
    float* OUT = (float*)d_out;

    // gfx950 allows up to 160 KB LDS per workgroup; opt in (idempotent, capture-safe).
    hipFuncSetAttribute((const void*)lstm_gen_kernel,
                        hipFuncAttributeMaxDynamicSharedMemorySize, LDS_BYTES);

    lstm_gen_kernel<<<dim3(GRID), dim3(BLK), LDS_BYTES, stream>>>(
        X, Wih1, Whh1, bih1, bhh1, Wih2, Whh2, bih2, bhh2, Wlin, blin, OUT);
}

// Round 2
// 5955.554 us; speedup vs baseline: 3.3260x; 3.3260x over previous
//
#include <hip/hip_runtime.h>

// ---------------------------------------------------------------------------
// 2-layer LSTM generator via f16 MFMA, persistent per-wave kernel.
//   grid 256 x 256thr (4 waves, 1/SIMD). Wave owns 16 batch columns for all
//   1024 steps -> NO barriers in the time loop (per-wave LDS exchange).
//   gates[208x16] = W[208xK] * u[Kx16] with 16x16x32 f16 MFMA.
//   W rows unit-major (i,f,g,o per unit) so the C-frag (col=lane&15,
//   row=4*(lane>>4)+reg) gives each lane all 4 gates of one unit.
//   W stored as single f16 A-frags in LDS (pre-arranged, 16B/lane reads);
//   activations stored packed (f16 hi | f16 lo)<<16, 2 MFMA terms per tile.
//   A/B frag k-maps are symmetric => any consistent position->k bijection
//   is correct.
// ---------------------------------------------------------------------------

typedef _Float16 half8 __attribute__((ext_vector_type(8)));
typedef float floatx4 __attribute__((ext_vector_type(4)));
typedef unsigned int u32;

#define H     50
#define F     3
#define T_TF  512
#define T_ALL 1024
#define BATCH 16384
#define WAVES 4
#define BLK   256
#define NB    16
#define BPB   (WAVES*NB)          // 64 batch / block
#define GRID  (BATCH/BPB)         // 256
#define MT    13                  // M tiles (208 gate rows)

#define A1_HALF (2*MT*512)        // 26 frags * 512 halves
#define A2_HALF (4*MT*512)        // 52 frags
#define AH_HALF (2*512)           // head: 2 frags
#define EX_STRIDE 17              // u32 row stride (bank decorrelation)
#define EX_U32  (128*EX_STRIDE)   // per-wave exchange: 128 rows x 17
#define LDS_BYTES ((A1_HALF+A2_HALF+AH_HALF)*2 + (208+208+16)*4 + WAVES*EX_U32*4)

__device__ __forceinline__ float fsig(float x){
    float e = __builtin_amdgcn_exp2f(-1.44269504089f*x);
    return __builtin_amdgcn_rcpf(1.0f + e);
}
__device__ __forceinline__ float ftanh(float x){
    float e = __builtin_amdgcn_exp2f(2.88539008178f*x);
    return 1.0f - 2.0f*__builtin_amdgcn_rcpf(1.0f + e);
}
__device__ __forceinline__ u32 packf16(float v){
    _Float16 h = (_Float16)v;
    _Float16 l = (_Float16)(v - (float)h);
    unsigned short hb = __builtin_bit_cast(unsigned short, h);
    unsigned short lb = __builtin_bit_cast(unsigned short, l);
    return (u32)hb | ((u32)lb << 16);
}
__device__ __forceinline__ _Float16 lo16(u32 w){ return __builtin_bit_cast(_Float16,(unsigned short)(w & 0xffffu)); }
__device__ __forceinline__ _Float16 hi16(u32 w){ return __builtin_bit_cast(_Float16,(unsigned short)(w >> 16)); }

__device__ __forceinline__ void buildB(const u32* EXw, int kb, int g, int nn,
                                       half8& Bh, half8& Bl){
    #pragma unroll
    for (int j = 0; j < 4; ++j){
        u32 w  = EXw[(kb + 4*g + j)*EX_STRIDE + nn];
        u32 w2 = EXw[(kb + 16 + 4*g + j)*EX_STRIDE + nn];
        Bh[j]   = lo16(w);  Bl[j]   = hi16(w);
        Bh[4+j] = lo16(w2); Bl[4+j] = hi16(w2);
    }
}

#define MFMA(a,b,c) __builtin_amdgcn_mfma_f32_16x16x32_f16((a),(b),(c),0,0,0)

extern "C" __global__ void __launch_bounds__(BLK, 1)
lstm_mfma_kernel(const float* __restrict__ X,
                 const float* __restrict__ Wih1, const float* __restrict__ Whh1,
                 const float* __restrict__ bih1, const float* __restrict__ bhh1,
                 const float* __restrict__ Wih2, const float* __restrict__ Whh2,
                 const float* __restrict__ bih2, const float* __restrict__ bhh2,
                 const float* __restrict__ Wlin, const float* __restrict__ blin,
                 float* __restrict__ OUT)
{
    extern __shared__ __align__(16) char ldsraw[];
    _Float16* A1 = (_Float16*)ldsraw;
    _Float16* A2 = A1 + A1_HALF;
    _Float16* Ah = A2 + A2_HALF;
    float* b1f = (float*)(Ah + AH_HALF);
    float* b2f = b1f + 208;
    float* bhf = b2f + 208;
    u32* EXall = (u32*)(bhf + 16);

    const int tid  = threadIdx.x;
    const int wave = tid >> 6, lane = tid & 63;
    const int g = lane >> 4, nn = lane & 15;
    const int bb = blockIdx.x * BPB + wave * NB;

    // ---------------- staging (once) ----------------
    // A1: u1 = [h1(0..49) | x(50..52) | 0(53..63)]
    for (int i = tid; i < A1_HALF; i += BLK) {
        int frag = i >> 9, r = i & 511;
        int l = r >> 3, j = r & 7;
        int kap = frag / MT, tau = frag % MT;
        int gg = l >> 4, m = l & 15;
        int kl = (j < 4) ? (4*gg + j) : (16 + 4*gg + j - 4);
        int k = 32*kap + kl;
        int M = 16*tau + m;
        int u = M >> 2, gi = M & 3;
        float v = 0.0f;
        if (u < H) {
            int tr = gi*H + u;
            if (k < H) v = Whh1[tr*H + k];
            else if (k < H + F) v = Wih1[tr*F + (k - H)];
        }
        A1[i] = (_Float16)v;
    }
    // A2: u2 = [h1(0..49) | 0(50..63) | h2(64..113) | 0(114..127)]
    for (int i = tid; i < A2_HALF; i += BLK) {
        int frag = i >> 9, r = i & 511;
        int l = r >> 3, j = r & 7;
        int kap = frag / MT, tau = frag % MT;
        int gg = l >> 4, m = l & 15;
        int kl = (j < 4) ? (4*gg + j) : (16 + 4*gg + j - 4);
        int k = 32*kap + kl;
        int M = 16*tau + m;
        int u = M >> 2, gi = M & 3;
        float v = 0.0f;
        if (u < H) {
            int tr = gi*H + u;
            if (k < H) v = Wih2[tr*H + k];                    // input = h1
            else if (k >= 64 && k < 64 + H) v = Whh2[tr*H + (k - 64)];
        }
        A2[i] = (_Float16)v;
    }
    // head: rows 0..2 = Wlin over h2 (u2 rows 64..127)
    for (int i = tid; i < AH_HALF; i += BLK) {
        int frag = i >> 9, r = i & 511;
        int l = r >> 3, j = r & 7;
        int gg = l >> 4, m = l & 15;
        int kl = (j < 4) ? (4*gg + j) : (16 + 4*gg + j - 4);
        int col = 32*frag + kl;                               // h2 unit index
        float v = (m < F && col < H) ? Wlin[m*H + col] : 0.0f;
        Ah[i] = (_Float16)v;
    }
    for (int i = tid; i < 208; i += BLK) {
        int u = i >> 2, gi = i & 3;
        float v1 = 0.0f, v2 = 0.0f;
        if (u < H) { v1 = bih1[gi*H + u] + bhh1[gi*H + u];
                     v2 = bih2[gi*H + u] + bhh2[gi*H + u]; }
        b1f[i] = v1; b2f[i] = v2;
    }
    for (int i = tid; i < 16; i += BLK) bhf[i] = (i < F) ? blin[i] : 0.0f;
    for (int i = tid; i < WAVES*EX_U32; i += BLK) EXall[i] = 0u;   // h=0, pads=0
    __syncthreads();

    u32* EXw = EXall + wave * EX_U32;
    const int xl_n = lane / 3, xl_o = lane - 3*(lane/3);

    float c1[MT], c2[MT];
    #pragma unroll
    for (int q = 0; q < MT; ++q) { c1[q] = 0.0f; c2[q] = 0.0f; }

    #pragma unroll 1
    for (int t = 0; t < T_ALL; ++t) {
        // ---- x rows: teacher phase loads X; gen phase keeps fed-back out ----
        if (t < T_TF) {
            if (lane < 48) {
                float xv = X[((size_t)t*BATCH + bb)*F + lane];
                EXw[(H + xl_o)*EX_STRIDE + xl_n] = packf16(xv);
            }
        }

        // ---- layer 1: gates = W1 * [h1_prev; x] ----
        floatx4 C[MT];
        #pragma unroll
        for (int tau = 0; tau < MT; ++tau)
            C[tau] = *(const floatx4*)(b1f + 16*tau + 4*g);
        #pragma unroll
        for (int kap = 0; kap < 2; ++kap) {
            half8 Bh, Bl;
            buildB(EXw, 32*kap, g, nn, Bh, Bl);
            #pragma unroll
            for (int tau = 0; tau < MT; ++tau) {
                half8 a = *(const half8*)(A1 + ((kap*MT + tau)*64 + lane)*8);
                C[tau] = MFMA(a, Bh, C[tau]);
                C[tau] = MFMA(a, Bl, C[tau]);
            }
        }
        #pragma unroll
        for (int tau = 0; tau < MT; ++tau) {
            float iv = fsig(C[tau][0]);
            float fv = fsig(C[tau][1]);
            float gv = ftanh(C[tau][2]);
            float ov = fsig(C[tau][3]);
            c1[tau] = fv*c1[tau] + iv*gv;
            float h = ov*ftanh(c1[tau]);
            int u = 4*tau + g;
            if (u < H) EXw[u*EX_STRIDE + nn] = packf16(h);
        }

        // ---- layer 2: gates = W2 * [h1_new; h2_prev] ----
        floatx4 D[MT];
        #pragma unroll
        for (int tau = 0; tau < MT; ++tau)
            D[tau] = *(const floatx4*)(b2f + 16*tau + 4*g);
        #pragma unroll
        for (int kap = 0; kap < 4; ++kap) {
            half8 Bh, Bl;
            buildB(EXw, 32*kap, g, nn, Bh, Bl);
            #pragma unroll
            for (int tau = 0; tau < MT; ++tau) {
                half8 a = *(const half8*)(A2 + ((kap*MT + tau)*64 + lane)*8);
                D[tau] = MFMA(a, Bh, D[tau]);
                D[tau] = MFMA(a, Bl, D[tau]);
            }
        }
        #pragma unroll
        for (int tau = 0; tau < MT; ++tau) {
            float iv = fsig(D[tau][0]);
            float fv = fsig(D[tau][1]);
            float gv = ftanh(D[tau][2]);
            float ov = fsig(D[tau][3]);
            c2[tau] = fv*c2[tau] + iv*gv;
            float h = ov*ftanh(c2[tau]);
            int u = 4*tau + g;
            if (u < H) EXw[(64 + u)*EX_STRIDE + nn] = packf16(h);
        }

        // ---- head: out = Wlin * h2_new + blin (fresh B frags of rows 64..127) ----
        floatx4 E = *(const floatx4*)(bhf + 4*g);
        #pragma unroll
        for (int kap = 0; kap < 2; ++kap) {
            half8 Bh, Bl;
            buildB(EXw, 64 + 32*kap, g, nn, Bh, Bl);
            half8 a = *(const half8*)(Ah + (kap*64 + lane)*8);
            E = MFMA(a, Bh, E);
            E = MFMA(a, Bl, E);
        }
        if (lane < 16) {   // rows 0..2 of head tile live in lanes 0..15, regs 0..2
            size_t ob = ((size_t)t*BATCH + bb + lane)*F;
            OUT[ob + 0] = E[0];
            OUT[ob + 1] = E[1];
            OUT[ob + 2] = E[2];
            EXw[(H + 0)*EX_STRIDE + lane] = packf16(E[0]);   // feedback -> next x
            EXw[(H + 1)*EX_STRIDE + lane] = packf16(E[1]);
            EXw[(H + 2)*EX_STRIDE + lane] = packf16(E[2]);
        }
    }
}

extern "C" void kernel_launch(void* const* d_in, const int* in_sizes, int n_in,
                              void* d_out, int out_size, void* d_ws, size_t ws_size,
                              hipStream_t stream) {
    (void)in_sizes; (void)n_in; (void)d_ws; (void)ws_size; (void)out_size;
    const float* X    = (const float*)d_in[0];
    const float* Wih1 = (const float*)d_in[1];
    const float* Whh1 = (const float*)d_in[2];
    const float* bih1 = (const float*)d_in[3];
    const float* bhh1 = (const float*)d_in[4];
    const float* Wih2 = (const float*)d_in[5];
    const float* Whh2 = (const float*)d_in[6];
    const float* bih2 = (const float*)d_in[7];
    const float* bhh2 = (const float*)d_in[8];
    const float* Wlin = (const float*)d_in[9];
    const float* blin = (const float*)d_in[10];
    float* OUT = (float*)d_out;

    hipFuncSetAttribute((const void*)lstm_mfma_kernel,
                        hipFuncAttributeMaxDynamicSharedMemorySize, LDS_BYTES);

    lstm_mfma_kernel<<<dim3(GRID), dim3(BLK), LDS_BYTES, stream>>>(
        X, Wih1, Whh1, bih1, bhh1, Wih2, Whh2, bih2, bhh2, Wlin, blin, OUT);
}